// Round 1
// baseline (884.047 us; speedup 1.0000x reference)
//
#include <hip/hip_runtime.h>
#include <math.h>

#define EPSV 1e-5f

constexpr int B = 32, D_ = 256, N = 1024;
constexpr int M = 1024, K = 16, H = 4, V = 64, KH = 64;

// ---------------- K1: keys & values projections ----------------
// keys stored [b][k][m] (transposed) so softmax over m reads contiguously.
// values stored [b][m][v].
__global__ __launch_bounds__(256) void proj_kv_kernel(
        const float* __restrict__ c, const float* __restrict__ Wk,
        const float* __restrict__ Wv, float* __restrict__ keys,
        float* __restrict__ vals) {
    const int b = blockIdx.x >> 5;
    const int m0 = (blockIdx.x & 31) * 32;
    const int t = threadIdx.x;
    __shared__ float c_lds[32 * 68];
    __shared__ float w_lds[80 * 68];
    const int m_loc = t & 31, grp = t >> 5;  // grp 0..7, 10 outputs each
    float acc[10];
#pragma unroll
    for (int j = 0; j < 10; ++j) acc[j] = 0.f;
    const float* crow = c + ((size_t)b * M + m0) * D_;
    for (int d0 = 0; d0 < D_; d0 += 64) {
#pragma unroll
        for (int r = 0; r < 8; ++r) {
            int idx = r * 256 + t;
            c_lds[(idx >> 6) * 68 + (idx & 63)] =
                crow[(size_t)(idx >> 6) * D_ + d0 + (idx & 63)];
        }
#pragma unroll
        for (int r = 0; r < 20; ++r) {
            int idx = r * 256 + t;
            int o = idx >> 6, dd = idx & 63;
            float w = (o < 16) ? Wk[o * D_ + d0 + dd] : Wv[(o - 16) * D_ + d0 + dd];
            w_lds[o * 68 + dd] = w;
        }
        __syncthreads();
#pragma unroll
        for (int d4 = 0; d4 < 16; ++d4) {
            float4 c4 = *(const float4*)&c_lds[m_loc * 68 + d4 * 4];
#pragma unroll
            for (int j = 0; j < 10; ++j) {
                float4 w4 = *(const float4*)&w_lds[(grp * 10 + j) * 68 + d4 * 4];
                acc[j] += c4.x * w4.x + c4.y * w4.y + c4.z * w4.z + c4.w * w4.w;
            }
        }
        __syncthreads();
    }
    const int m = m0 + m_loc;
#pragma unroll
    for (int j = 0; j < 10; ++j) {
        int o = grp * 10 + j;
        if (o < 16)
            keys[((size_t)b * K + o) * M + m] = acc[j];
        else
            vals[((size_t)b * M + m) * V + (o - 16)] = acc[j];
    }
}

// ---------------- K2: softmax over m (per (b,k) column) ----------------
__global__ __launch_bounds__(256) void softmax_m_kernel(float* __restrict__ keys) {
    float* col = keys + (size_t)blockIdx.x * M;  // [b][k][m] contiguous in m
    const int t = threadIdx.x;
    float x[4];
#pragma unroll
    for (int r = 0; r < 4; ++r) x[r] = col[t + r * 256];
    float mx = fmaxf(fmaxf(x[0], x[1]), fmaxf(x[2], x[3]));
#pragma unroll
    for (int off = 32; off > 0; off >>= 1) mx = fmaxf(mx, __shfl_xor(mx, off));
    __shared__ float rmax[4];
    if ((t & 63) == 0) rmax[t >> 6] = mx;
    __syncthreads();
    mx = fmaxf(fmaxf(rmax[0], rmax[1]), fmaxf(rmax[2], rmax[3]));
    float s = 0.f;
#pragma unroll
    for (int r = 0; r < 4; ++r) {
        x[r] = __expf(x[r] - mx);
        s += x[r];
    }
#pragma unroll
    for (int off = 32; off > 0; off >>= 1) s += __shfl_xor(s, off);
    __shared__ float rsum[4];
    if ((t & 63) == 0) rsum[t >> 6] = s;
    __syncthreads();
    s = rsum[0] + rsum[1] + rsum[2] + rsum[3];
    const float inv = 1.f / s;
#pragma unroll
    for (int r = 0; r < 4; ++r) col[t + r * 256] = x[r] * inv;
}

// ---------------- K3: BatchNorm1d over values, per-m channel ----------------
__global__ __launch_bounds__(256) void bn_values_kernel(
        float* __restrict__ vals, const float* __restrict__ gamma,
        const float* __restrict__ beta) {
    const int m = blockIdx.x, t = threadIdx.x;
    float xv[8];
    float s = 0.f, ss = 0.f;
#pragma unroll
    for (int r = 0; r < 8; ++r) {
        int idx = r * 256 + t;
        int b = idx >> 6, v = idx & 63;
        float val = vals[((size_t)b * M + m) * V + v];
        xv[r] = val;
        s += val;
        ss += val * val;
    }
#pragma unroll
    for (int off = 32; off > 0; off >>= 1) {
        s += __shfl_xor(s, off);
        ss += __shfl_xor(ss, off);
    }
    __shared__ float rs[4], rss[4];
    if ((t & 63) == 0) {
        rs[t >> 6] = s;
        rss[t >> 6] = ss;
    }
    __syncthreads();
    s = rs[0] + rs[1] + rs[2] + rs[3];
    ss = rss[0] + rss[1] + rss[2] + rss[3];
    const float mean = s * (1.f / 2048.f);
    const float var = ss * (1.f / 2048.f) - mean * mean;
    const float g = gamma[m] * rsqrtf(var + EPSV);
    const float bt = beta[m] - mean * g;
#pragma unroll
    for (int r = 0; r < 8; ++r) {
        int idx = r * 256 + t;
        int b = idx >> 6, v = idx & 63;
        vals[((size_t)b * M + m) * V + v] = xv[r] * g + bt;
    }
}

// ---------------- K4: query projection + per-k BN stats ----------------
// q stored [b][n][kh] with kh = k*4+h. Stats (sum,sumsq per k) via atomics.
__global__ __launch_bounds__(256) void proj_q_kernel(
        const float* __restrict__ x, const float* __restrict__ Wq,
        float* __restrict__ q, float* __restrict__ qstats) {
    const int b = blockIdx.x >> 5;
    const int n0 = (blockIdx.x & 31) * 32;
    const int t = threadIdx.x;
    __shared__ float c_lds[32 * 68];
    __shared__ float w_lds[64 * 68];
    const int n_loc = t & 31, grp = t >> 5;  // 8 outputs per thread
    float acc[8];
#pragma unroll
    for (int j = 0; j < 8; ++j) acc[j] = 0.f;
    const float* xrow = x + ((size_t)b * N + n0) * D_;  // xf reinterpret of x
    for (int d0 = 0; d0 < D_; d0 += 64) {
#pragma unroll
        for (int r = 0; r < 8; ++r) {
            int idx = r * 256 + t;
            c_lds[(idx >> 6) * 68 + (idx & 63)] =
                xrow[(size_t)(idx >> 6) * D_ + d0 + (idx & 63)];
        }
#pragma unroll
        for (int r = 0; r < 16; ++r) {
            int idx = r * 256 + t;
            int o = idx >> 6, dd = idx & 63;
            w_lds[o * 68 + dd] = Wq[o * D_ + d0 + dd];
        }
        __syncthreads();
#pragma unroll
        for (int d4 = 0; d4 < 16; ++d4) {
            float4 c4 = *(const float4*)&c_lds[n_loc * 68 + d4 * 4];
#pragma unroll
            for (int j = 0; j < 8; ++j) {
                float4 w4 = *(const float4*)&w_lds[(grp * 8 + j) * 68 + d4 * 4];
                acc[j] += c4.x * w4.x + c4.y * w4.y + c4.z * w4.z + c4.w * w4.w;
            }
        }
        __syncthreads();
    }
    const int n = n0 + n_loc;
    float* qrow = q + ((size_t)b * N + n) * KH;
    float ps[2] = {0.f, 0.f}, pss[2] = {0.f, 0.f};
#pragma unroll
    for (int j = 0; j < 8; ++j) {
        int o = grp * 8 + j;
        qrow[o] = acc[j];
        int w = j >> 2;  // k = o>>2 = grp*2 + (j>>2)
        ps[w] += acc[j];
        pss[w] += acc[j] * acc[j];
    }
    __shared__ float s_sum[16], s_ssq[16];
    if (t < 16) {
        s_sum[t] = 0.f;
        s_ssq[t] = 0.f;
    }
    __syncthreads();
    atomicAdd(&s_sum[grp * 2], ps[0]);
    atomicAdd(&s_ssq[grp * 2], pss[0]);
    atomicAdd(&s_sum[grp * 2 + 1], ps[1]);
    atomicAdd(&s_ssq[grp * 2 + 1], pss[1]);
    __syncthreads();
    if (t < 16) {
        atomicAdd(&qstats[t], s_sum[t]);
        atomicAdd(&qstats[16 + t], s_ssq[t]);
    }
}

// ---------------- K5: content_lambda[b][k][v] ----------------
__global__ __launch_bounds__(256) void content_lambda_kernel(
        const float* __restrict__ sk, const float* __restrict__ vals,
        float* __restrict__ cl) {
    const int b = blockIdx.x, t = threadIdx.x;
    const int v = t & 63, g = t >> 6;
    __shared__ float sk_lds[16 * 17];
    __shared__ float v_lds[16 * 64];
    float acc[4] = {0.f, 0.f, 0.f, 0.f};
    for (int m0 = 0; m0 < M; m0 += 16) {
        {
            int k = t >> 4, j = t & 15;
            sk_lds[k * 17 + j] = sk[((size_t)b * K + k) * M + m0 + j];
        }
#pragma unroll
        for (int r = 0; r < 4; ++r) {
            int idx = r * 256 + t;
            v_lds[idx] = vals[((size_t)b * M + m0 + (idx >> 6)) * V + (idx & 63)];
        }
        __syncthreads();
#pragma unroll
        for (int j = 0; j < 16; ++j) {
            float val = v_lds[j * 64 + v];
#pragma unroll
            for (int jj = 0; jj < 4; ++jj) acc[jj] += sk_lds[(g * 4 + jj) * 17 + j] * val;
        }
        __syncthreads();
    }
#pragma unroll
    for (int jj = 0; jj < 4; ++jj)
        cl[((size_t)b * K + g * 4 + jj) * V + v] = acc[jj];
}

// ---------------- K6: fused position + content output ----------------
// Block = (b, tile of 32 n). acc[n..][h][v] over m-loop; write [b][h*64+v][n].
__global__ __launch_bounds__(256) void fused_out_kernel(
        const float* __restrict__ q, const float* __restrict__ E,
        const float* __restrict__ vals, const float* __restrict__ cl,
        const float* __restrict__ qstats, const float* __restrict__ gq,
        const float* __restrict__ bq, float* __restrict__ out) {
    const int bid = blockIdx.x;
    const int b = bid & 31, nt = bid >> 5;  // 32 consecutive blocks share nt -> E L2 reuse
    const int n0 = nt * 32;
    const int t = threadIdx.x;

    __shared__ float smem[8960];
    float* qn = smem;                      // [32][68]  normalized queries (n, kh)
    float* El = smem + 2176;               // [32][132] E chunk (n, 8m*16k)
    float4* Tl = (float4*)(smem + 6400);   // [8][32]   T (m_loc, n) x 4h
    float* vl = smem + 7424;               // [8][64]   values chunk
    float* cll = smem + 7936;              // [16][64]  content lambda

    // stage normalized queries
    const float* qrow = q + ((size_t)b * N + n0) * KH;
#pragma unroll
    for (int r = 0; r < 8; ++r) {
        int idx = r * 256 + t;
        int n_loc = idx >> 6, kh = idx & 63;
        int k = kh >> 2;
        float mn = qstats[k] * (1.f / 131072.f);
        float var = qstats[16 + k] * (1.f / 131072.f) - mn * mn;
        float rstd = rsqrtf(var + EPSV);
        qn[n_loc * 68 + kh] = (qrow[(size_t)n_loc * KH + kh] - mn) * rstd * gq[k] + bq[k];
    }
#pragma unroll
    for (int r = 0; r < 4; ++r) {
        int idx = r * 256 + t;
        cll[idx] = cl[(size_t)b * K * V + idx];
    }
    __syncthreads();

    const int v = t & 63, g = t >> 6;
    // content term init: acc[i].{x,y,z,w} = h components for n = g+4i
    float4 acc[8];
#pragma unroll
    for (int i = 0; i < 8; ++i) {
        int n_loc = g + 4 * i;
        float4 a = {0.f, 0.f, 0.f, 0.f};
#pragma unroll
        for (int k = 0; k < 16; ++k) {
            float4 q4 = *(const float4*)&qn[n_loc * 68 + k * 4];
            float cc = cll[k * 64 + v];
            a.x += q4.x * cc;
            a.y += q4.y * cc;
            a.z += q4.z * cc;
            a.w += q4.w * cc;
        }
        acc[i] = a;
    }

    const float* Eb = E + (size_t)n0 * M * K;
    const float* vb = vals + (size_t)b * M * V;
    for (int m0 = 0; m0 < M; m0 += 8) {
        // stage E[n0+n][m0..m0+8)[k] : 128 contiguous floats per n
        {
            int n_loc = t >> 3, seg = t & 7;
            const float4* src = (const float4*)(Eb + (size_t)n_loc * M * K + m0 * K + seg * 16);
            float4* dst = (float4*)&El[n_loc * 132 + seg * 16];
#pragma unroll
            for (int r = 0; r < 4; ++r) dst[r] = src[r];
        }
        // stage values rows m0..m0+8
        vl[t] = vb[(size_t)m0 * V + t];
        vl[t + 256] = vb[(size_t)m0 * V + t + 256];
        __syncthreads();
        // T[j][n][h] = sum_k E[n][j*16+k] * qn[n][k*4+h]
        {
            int n_loc = t & 31, j = t >> 5;
            float4 Tv = {0.f, 0.f, 0.f, 0.f};
#pragma unroll
            for (int k = 0; k < 16; ++k) {
                float e = El[n_loc * 132 + j * 16 + k];
                float4 q4 = *(const float4*)&qn[n_loc * 68 + k * 4];
                Tv.x += e * q4.x;
                Tv.y += e * q4.y;
                Tv.z += e * q4.z;
                Tv.w += e * q4.w;
            }
            Tl[j * 32 + n_loc] = Tv;
        }
        __syncthreads();
        // acc[n][h] += T[j][n][h] * values[j][v]
#pragma unroll
        for (int j = 0; j < 8; ++j) {
            float val = vl[j * 64 + v];
#pragma unroll
            for (int i = 0; i < 8; ++i) {
                float4 T4 = Tl[j * 32 + g + 4 * i];
                acc[i].x += T4.x * val;
                acc[i].y += T4.y * val;
                acc[i].z += T4.z * val;
                acc[i].w += T4.w * val;
            }
        }
        __syncthreads();
    }

    // transpose through LDS for coalesced output writes
    float* ol = smem;  // [256][33] : (h*64+v) x n
#pragma unroll
    for (int i = 0; i < 8; ++i) {
        int n_loc = g + 4 * i;
        float av[4] = {acc[i].x, acc[i].y, acc[i].z, acc[i].w};
#pragma unroll
        for (int h = 0; h < 4; ++h) ol[(h * 64 + v) * 33 + n_loc] = av[h];
    }
    __syncthreads();
    float* ob = out + (size_t)b * D_ * N + n0;
#pragma unroll
    for (int r = 0; r < 32; ++r) {
        int idx = r * 256 + t;
        int dd = idx >> 5, n_loc = idx & 31;
        ob[(size_t)dd * N + n_loc] = ol[dd * 33 + n_loc];
    }
}

extern "C" void kernel_launch(void* const* d_in, const int* in_sizes, int n_in,
                              void* d_out, int out_size, void* d_ws, size_t ws_size,
                              hipStream_t stream) {
    const float* x = (const float*)d_in[0];
    const float* c = (const float*)d_in[1];
    const float* Wq = (const float*)d_in[2];
    const float* Wk = (const float*)d_in[3];
    const float* Wv = (const float*)d_in[4];
    const float* E = (const float*)d_in[5];
    const float* gv = (const float*)d_in[6];
    const float* bv = (const float*)d_in[7];
    const float* gq = (const float*)d_in[8];
    const float* bq = (const float*)d_in[9];
    float* out = (float*)d_out;
    float* ws = (float*)d_ws;

    float* sk = ws;                    // 32*16*1024      = 524288
    float* vals = ws + 524288;         // 32*1024*64      = 2097152
    float* qbuf = ws + 2621440;        // 32*1024*64      = 2097152
    float* cl = ws + 4718592;          // 32*16*64        = 32768
    float* qstats = ws + 4751360;      // 32 (sum16+ssq16)

    hipMemsetAsync(qstats, 0, 32 * sizeof(float), stream);

    proj_kv_kernel<<<1024, 256, 0, stream>>>(c, Wk, Wv, sk, vals);
    softmax_m_kernel<<<B * K, 256, 0, stream>>>(sk);
    bn_values_kernel<<<M, 256, 0, stream>>>(vals, gv, bv);
    proj_q_kernel<<<1024, 256, 0, stream>>>(x, Wq, qbuf, qstats);
    content_lambda_kernel<<<B, 256, 0, stream>>>(sk, vals, cl);
    fused_out_kernel<<<1024, 256, 0, stream>>>(qbuf, E, vals, cl, qstats, gq, bq, out);
}

// Round 6
// 515.611 us; speedup vs baseline: 1.7146x; 1.7146x over previous
//
#include <hip/hip_runtime.h>
#include <math.h>

#define EPSV 1e-5f

constexpr int B = 32, D_ = 256, N = 1024;
constexpr int M = 1024, K = 16, H = 4, V = 64, KH = 64;
constexpr int VT_STRIDE = 1056;  // valsT row: 1024 m + 16 cl + 16 zero-pad

typedef __bf16 bf16v8 __attribute__((ext_vector_type(8)));
typedef float f32x4 __attribute__((ext_vector_type(4)));
typedef unsigned short us4 __attribute__((ext_vector_type(4)));
typedef unsigned short us8 __attribute__((ext_vector_type(8)));

static __device__ __forceinline__ unsigned short bfb(float f) {
    return __builtin_bit_cast(unsigned short, (__bf16)f);
}
static __device__ __forceinline__ float bf2f(unsigned short u) {
    return __uint_as_float(((unsigned)u) << 16);
}

// ---------------- K1: keys & values projections ----------------
__global__ __launch_bounds__(256) void proj_kv_kernel(
        const float* __restrict__ c, const float* __restrict__ Wk,
        const float* __restrict__ Wv, float* __restrict__ keys,
        float* __restrict__ vals) {
    const int b = blockIdx.x >> 5;
    const int m0 = (blockIdx.x & 31) * 32;
    const int t = threadIdx.x;
    __shared__ float c_lds[32 * 68];
    __shared__ float w_lds[80 * 68];
    const int m_loc = t & 31, grp = t >> 5;
    float acc[10];
#pragma unroll
    for (int j = 0; j < 10; ++j) acc[j] = 0.f;
    const float* crow = c + ((size_t)b * M + m0) * D_;
    for (int d0 = 0; d0 < D_; d0 += 64) {
#pragma unroll
        for (int r = 0; r < 8; ++r) {
            int idx = r * 256 + t;
            c_lds[(idx >> 6) * 68 + (idx & 63)] =
                crow[(size_t)(idx >> 6) * D_ + d0 + (idx & 63)];
        }
#pragma unroll
        for (int r = 0; r < 20; ++r) {
            int idx = r * 256 + t;
            int o = idx >> 6, dd = idx & 63;
            float w = (o < 16) ? Wk[o * D_ + d0 + dd] : Wv[(o - 16) * D_ + d0 + dd];
            w_lds[o * 68 + dd] = w;
        }
        __syncthreads();
#pragma unroll
        for (int d4 = 0; d4 < 16; ++d4) {
            float4 c4 = *(const float4*)&c_lds[m_loc * 68 + d4 * 4];
#pragma unroll
            for (int j = 0; j < 10; ++j) {
                float4 w4 = *(const float4*)&w_lds[(grp * 10 + j) * 68 + d4 * 4];
                acc[j] += c4.x * w4.x + c4.y * w4.y + c4.z * w4.z + c4.w * w4.w;
            }
        }
        __syncthreads();
    }
    const int m = m0 + m_loc;
#pragma unroll
    for (int j = 0; j < 10; ++j) {
        int o = grp * 10 + j;
        if (o < 16)
            keys[((size_t)b * K + o) * M + m] = acc[j];
        else
            vals[((size_t)b * M + m) * V + (o - 16)] = acc[j];
    }
}

// ---------------- K2: softmax over m ----------------
__global__ __launch_bounds__(256) void softmax_m_kernel(float* __restrict__ keys) {
    float* col = keys + (size_t)blockIdx.x * M;
    const int t = threadIdx.x;
    float x[4];
#pragma unroll
    for (int r = 0; r < 4; ++r) x[r] = col[t + r * 256];
    float mx = fmaxf(fmaxf(x[0], x[1]), fmaxf(x[2], x[3]));
#pragma unroll
    for (int off = 32; off > 0; off >>= 1) mx = fmaxf(mx, __shfl_xor(mx, off));
    __shared__ float rmax[4];
    if ((t & 63) == 0) rmax[t >> 6] = mx;
    __syncthreads();
    mx = fmaxf(fmaxf(rmax[0], rmax[1]), fmaxf(rmax[2], rmax[3]));
    float s = 0.f;
#pragma unroll
    for (int r = 0; r < 4; ++r) {
        x[r] = __expf(x[r] - mx);
        s += x[r];
    }
#pragma unroll
    for (int off = 32; off > 0; off >>= 1) s += __shfl_xor(s, off);
    __shared__ float rsum[4];
    if ((t & 63) == 0) rsum[t >> 6] = s;
    __syncthreads();
    s = rsum[0] + rsum[1] + rsum[2] + rsum[3];
    const float inv = 1.f / s;
#pragma unroll
    for (int r = 0; r < 4; ++r) col[t + r * 256] = x[r] * inv;
}

// ---------------- K3: BatchNorm1d over values ----------------
__global__ __launch_bounds__(256) void bn_values_kernel(
        float* __restrict__ vals, const float* __restrict__ gamma,
        const float* __restrict__ beta) {
    const int m = blockIdx.x, t = threadIdx.x;
    float xv[8];
    float s = 0.f, ss = 0.f;
#pragma unroll
    for (int r = 0; r < 8; ++r) {
        int idx = r * 256 + t;
        int b = idx >> 6, v = idx & 63;
        float val = vals[((size_t)b * M + m) * V + v];
        xv[r] = val;
        s += val;
        ss += val * val;
    }
#pragma unroll
    for (int off = 32; off > 0; off >>= 1) {
        s += __shfl_xor(s, off);
        ss += __shfl_xor(ss, off);
    }
    __shared__ float rs[4], rss[4];
    if ((t & 63) == 0) {
        rs[t >> 6] = s;
        rss[t >> 6] = ss;
    }
    __syncthreads();
    s = rs[0] + rs[1] + rs[2] + rs[3];
    ss = rss[0] + rss[1] + rss[2] + rss[3];
    const float mean = s * (1.f / 2048.f);
    const float var = ss * (1.f / 2048.f) - mean * mean;
    const float g = gamma[m] * rsqrtf(var + EPSV);
    const float bt = beta[m] - mean * g;
#pragma unroll
    for (int r = 0; r < 8; ++r) {
        int idx = r * 256 + t;
        int b = idx >> 6, v = idx & 63;
        vals[((size_t)b * M + m) * V + v] = xv[r] * g + bt;
    }
}

// ---------------- K3b: transpose normalized values -> bf16 [b][v][m] ----------------
__global__ __launch_bounds__(256) void valsT_kernel(const float* __restrict__ vals,
                                                    unsigned short* __restrict__ valsT) {
    const int b = blockIdx.x >> 4;
    const int m0 = (blockIdx.x & 15) * 64;
    const int t = threadIdx.x;
    __shared__ unsigned short tile[64][72];
    {
        const int mm = t >> 2, vs = (t & 3) * 16;
        const float* src = vals + ((size_t)b * M + m0 + mm) * V + vs;
#pragma unroll
        for (int r = 0; r < 4; ++r) {
            float4 f = *(const float4*)(src + r * 4);
            tile[vs + r * 4 + 0][mm] = bfb(f.x);
            tile[vs + r * 4 + 1][mm] = bfb(f.y);
            tile[vs + r * 4 + 2][mm] = bfb(f.z);
            tile[vs + r * 4 + 3][mm] = bfb(f.w);
        }
    }
    __syncthreads();
    const int v = t >> 2, ms2 = (t & 3) * 16;
    unsigned short* dst = valsT + ((size_t)b * 64 + v) * VT_STRIDE + m0 + ms2;
    *(us8*)(dst) = *(const us8*)&tile[v][ms2];
    *(us8*)(dst + 8) = *(const us8*)&tile[v][ms2 + 8];
}

// ---------------- K4: query projection + per-k BN stats ----------------
__global__ __launch_bounds__(256) void proj_q_kernel(
        const float* __restrict__ x, const float* __restrict__ Wq,
        float* __restrict__ q, float* __restrict__ qstats) {
    const int b = blockIdx.x >> 5;
    const int n0 = (blockIdx.x & 31) * 32;
    const int t = threadIdx.x;
    __shared__ float c_lds[32 * 68];
    __shared__ float w_lds[64 * 68];
    const int n_loc = t & 31, grp = t >> 5;
    float acc[8];
#pragma unroll
    for (int j = 0; j < 8; ++j) acc[j] = 0.f;
    const float* xrow = x + ((size_t)b * N + n0) * D_;
    for (int d0 = 0; d0 < D_; d0 += 64) {
#pragma unroll
        for (int r = 0; r < 8; ++r) {
            int idx = r * 256 + t;
            c_lds[(idx >> 6) * 68 + (idx & 63)] =
                xrow[(size_t)(idx >> 6) * D_ + d0 + (idx & 63)];
        }
#pragma unroll
        for (int r = 0; r < 16; ++r) {
            int idx = r * 256 + t;
            int o = idx >> 6, dd = idx & 63;
            w_lds[o * 68 + dd] = Wq[o * D_ + d0 + dd];
        }
        __syncthreads();
#pragma unroll
        for (int d4 = 0; d4 < 16; ++d4) {
            float4 c4 = *(const float4*)&c_lds[n_loc * 68 + d4 * 4];
#pragma unroll
            for (int j = 0; j < 8; ++j) {
                float4 w4 = *(const float4*)&w_lds[(grp * 8 + j) * 68 + d4 * 4];
                acc[j] += c4.x * w4.x + c4.y * w4.y + c4.z * w4.z + c4.w * w4.w;
            }
        }
        __syncthreads();
    }
    const int n = n0 + n_loc;
    float* qrow = q + ((size_t)b * N + n) * KH;
    float ps[2] = {0.f, 0.f}, pss[2] = {0.f, 0.f};
#pragma unroll
    for (int j = 0; j < 8; ++j) {
        int o = grp * 8 + j;
        qrow[o] = acc[j];
        int w = j >> 2;
        ps[w] += acc[j];
        pss[w] += acc[j] * acc[j];
    }
    __shared__ float s_sum[16], s_ssq[16];
    if (t < 16) {
        s_sum[t] = 0.f;
        s_ssq[t] = 0.f;
    }
    __syncthreads();
    atomicAdd(&s_sum[grp * 2], ps[0]);
    atomicAdd(&s_ssq[grp * 2], pss[0]);
    atomicAdd(&s_sum[grp * 2 + 1], ps[1]);
    atomicAdd(&s_ssq[grp * 2 + 1], pss[1]);
    __syncthreads();
    if (t < 16) {
        atomicAdd(&qstats[t], s_sum[t]);
        atomicAdd(&qstats[16 + t], s_ssq[t]);
    }
}

// ---------------- K5: content_lambda -> bf16 tail of valsT ----------------
__global__ __launch_bounds__(256) void content_lambda_kernel(
        const float* __restrict__ sk, const float* __restrict__ vals,
        unsigned short* __restrict__ valsT) {
    const int b = blockIdx.x, t = threadIdx.x;
    const int v = t & 63, g = t >> 6;
    __shared__ float sk_lds[16 * 17];
    __shared__ float v_lds[16 * 64];
    float acc[4] = {0.f, 0.f, 0.f, 0.f};
    for (int m0 = 0; m0 < M; m0 += 16) {
        {
            int k = t >> 4, j = t & 15;
            sk_lds[k * 17 + j] = sk[((size_t)b * K + k) * M + m0 + j];
        }
#pragma unroll
        for (int r = 0; r < 4; ++r) {
            int idx = r * 256 + t;
            v_lds[idx] = vals[((size_t)b * M + m0 + (idx >> 6)) * V + (idx & 63)];
        }
        __syncthreads();
#pragma unroll
        for (int j = 0; j < 16; ++j) {
            float val = v_lds[j * 64 + v];
#pragma unroll
            for (int jj = 0; jj < 4; ++jj) acc[jj] += sk_lds[(g * 4 + jj) * 17 + j] * val;
        }
        __syncthreads();
    }
#pragma unroll
    for (int jj = 0; jj < 4; ++jj) {
        int kk = g * 4 + jj;
        valsT[((size_t)b * 64 + v) * VT_STRIDE + 1024 + kk] = bfb(acc[jj]);
        valsT[((size_t)b * 64 + v) * VT_STRIDE + 1040 + kk] = 0;
    }
}

// ---------------- K5b: E -> bf16 ----------------
__global__ __launch_bounds__(256) void e16_kernel(const float* __restrict__ E,
                                                  unsigned short* __restrict__ E16) {
    size_t i = ((size_t)blockIdx.x * 256 + threadIdx.x) * 8;
    float4 a = *(const float4*)(E + i);
    float4 c4 = *(const float4*)(E + i + 4);
    us8 o = {bfb(a.x), bfb(a.y), bfb(a.z), bfb(a.w),
             bfb(c4.x), bfb(c4.y), bfb(c4.z), bfb(c4.w)};
    *(us8*)(E16 + i) = o;
}

// ---------------- K6: fused position+content via MFMA ----------------
// Block = (b, 32-n tile), 4 waves. Per 32-m chunk: VALU computes
// T[nh=4n+h][m] = sum_k E[n][m][k]*qn[n][k][h] -> bf16 LDS (dbuf, stride 40);
// MFMA accumulates D[nh][v] += T[nh][m-chunk] @ valsT[v][m-chunk]^T.
// 33rd chunk appends content term (A=qn, B=cl^T).
template <bool USE_E16>
__global__ __launch_bounds__(256, 2) void fused_mfma_kernel(
        const float* __restrict__ qb, const float* __restrict__ Ef,
        const unsigned short* __restrict__ E16,
        const unsigned short* __restrict__ valsT,
        const float* __restrict__ qstats, const float* __restrict__ gq,
        const float* __restrict__ bq, float* __restrict__ out) {
    const int bid = blockIdx.x;
    const int b = bid & 31, nt = bid >> 5;  // 32 consecutive blocks share the E slice
    const int n0 = nt * 32;
    const int t = threadIdx.x;
    const int w = t >> 6, lane = t & 63;
    const int li = lane & 15, lg = lane >> 4;
    const int n_loc = t >> 3, ms = (t & 7) * 4;

    __shared__ unsigned short T_lds[2][128 * 40];
    __shared__ unsigned short vl[2][64 * 40];
    __shared__ float qn_lds[32 * 68];

    // normalized q row for this thread's n (held in 64 VGPRs)
    float4 q4s[16];
    {
        const float* qrow = qb + ((size_t)b * N + n0 + n_loc) * KH;
#pragma unroll
        for (int k = 0; k < 16; ++k) {
            float mn = qstats[k] * (1.f / 131072.f);
            float var = qstats[16 + k] * (1.f / 131072.f) - mn * mn;
            float sc = rsqrtf(var + EPSV) * gq[k];
            float bb = bq[k] - mn * sc;
            float4 v4 = *(const float4*)(qrow + k * 4);
            q4s[k] = make_float4(v4.x * sc + bb, v4.y * sc + bb,
                                 v4.z * sc + bb, v4.w * sc + bb);
        }
    }
    if ((t & 7) == 0) {
#pragma unroll
        for (int k = 0; k < 16; ++k) *(float4*)&qn_lds[n_loc * 68 + k * 4] = q4s[k];
    }

    f32x4 acc[2][4];
#pragma unroll
    for (int a = 0; a < 2; ++a)
#pragma unroll
        for (int vt = 0; vt < 4; ++vt) acc[a][vt] = (f32x4){0.f, 0.f, 0.f, 0.f};

    const size_t erow_base = (size_t)(n0 + n_loc) * M * 16;

    int pb = 0;
    for (int ch = 0; ch < 33; ++ch) {
        const int m0 = ch * 32;
        // issue E loads early (registers; each E element used exactly once)
        us8 ev8[8];
        float4 ev4[16];
        if (ch < 32) {
            if (USE_E16) {
                const us8* ep = (const us8*)(E16 + erow_base + (size_t)(m0 + ms) * 16);
#pragma unroll
                for (int r = 0; r < 8; ++r) ev8[r] = ep[r];
            } else {
                const float4* ep = (const float4*)(Ef + erow_base + (size_t)(m0 + ms) * 16);
#pragma unroll
                for (int r = 0; r < 16; ++r) ev4[r] = ep[r];
            }
        }
        // stage vals chunk -> LDS (64 v rows x 32 m, padded stride 40)
        {
            const int vv = t >> 2, jj = t & 3;
            const us8* src = (const us8*)(valsT + ((size_t)b * 64 + vv) * VT_STRIDE + m0 + jj * 8);
            *(us8*)&vl[pb][vv * 40 + jj * 8] = *src;
        }
        // T compute + bf16 pack into LDS
        if (ch < 32) {
            float tacc[4][4];
#pragma unroll
            for (int i = 0; i < 4; ++i) {
                tacc[i][0] = 0.f; tacc[i][1] = 0.f; tacc[i][2] = 0.f; tacc[i][3] = 0.f;
            }
#pragma unroll
            for (int k = 0; k < 16; ++k) {
                const float4 qk = q4s[k];
#pragma unroll
                for (int i = 0; i < 4; ++i) {
                    float e;
                    if (USE_E16) {
                        const int fl = i * 16 + k;
                        unsigned short u = ev8[fl >> 3][fl & 7];
                        e = bf2f(u);
                    } else {
                        const int fl = i * 16 + k;
                        const float* evp = (const float*)&ev4[fl >> 2];
                        e = evp[fl & 3];
                    }
                    tacc[i][0] += e * qk.x;
                    tacc[i][1] += e * qk.y;
                    tacc[i][2] += e * qk.z;
                    tacc[i][3] += e * qk.w;
                }
            }
#pragma unroll
            for (int h = 0; h < 4; ++h) {
                us4 pk = {bfb(tacc[0][h]), bfb(tacc[1][h]), bfb(tacc[2][h]), bfb(tacc[3][h])};
                *(us4*)&T_lds[pb][(4 * n_loc + h) * 40 + ms] = pk;
            }
        } else {
            // content chunk: T[4n+h][mm] = qn[n][mm*4+h] for mm<16 else 0
#pragma unroll
            for (int h = 0; h < 4; ++h) {
                us4 pk;
#pragma unroll
                for (int i = 0; i < 4; ++i) {
                    int mm = ms + i;
                    float val = (mm < 16) ? qn_lds[n_loc * 68 + mm * 4 + h] : 0.f;
                    pk[i] = bfb(val);
                }
                *(us4*)&T_lds[pb][(4 * n_loc + h) * 40 + ms] = pk;
            }
        }
        __syncthreads();
        // MFMA: 2 A-tiles (nh chunk of this wave) x 4 v-tiles
        bf16v8 af[2], bfr[4];
#pragma unroll
        for (int a = 0; a < 2; ++a)
            af[a] = *(const bf16v8*)&T_lds[pb][(w * 32 + a * 16 + li) * 40 + lg * 8];
#pragma unroll
        for (int vt = 0; vt < 4; ++vt)
            bfr[vt] = *(const bf16v8*)&vl[pb][(vt * 16 + li) * 40 + lg * 8];
#pragma unroll
        for (int a = 0; a < 2; ++a)
#pragma unroll
            for (int vt = 0; vt < 4; ++vt)
                acc[a][vt] = __builtin_amdgcn_mfma_f32_16x16x32_bf16(
                    af[a], bfr[vt], acc[a][vt], 0, 0, 0);
        pb ^= 1;
    }

    // epilogue: C/D layout col=li (v), row=lg*4+r (nh) -> coalesced stores
    float* ob = out + (size_t)b * D_ * N;
#pragma unroll
    for (int a = 0; a < 2; ++a) {
#pragma unroll
        for (int vt = 0; vt < 4; ++vt) {
#pragma unroll
            for (int r = 0; r < 4; ++r) {
                int nh = w * 32 + a * 16 + lg * 4 + r;
                ob[(size_t)((nh & 3) * 64 + vt * 16 + li) * N + n0 + (nh >> 2)] =
                    acc[a][vt][r];
            }
        }
    }
}

extern "C" void kernel_launch(void* const* d_in, const int* in_sizes, int n_in,
                              void* d_out, int out_size, void* d_ws, size_t ws_size,
                              hipStream_t stream) {
    const float* x = (const float*)d_in[0];
    const float* c = (const float*)d_in[1];
    const float* Wq = (const float*)d_in[2];
    const float* Wk = (const float*)d_in[3];
    const float* Wv = (const float*)d_in[4];
    const float* E = (const float*)d_in[5];
    const float* gv = (const float*)d_in[6];
    const float* bv = (const float*)d_in[7];
    const float* gq = (const float*)d_in[8];
    const float* bq = (const float*)d_in[9];
    float* out = (float*)d_out;
    float* ws = (float*)d_ws;

    float* sk = ws;                                       // 524288 f
    float* vals = ws + 524288;                            // 2097152 f
    float* qbuf = ws + 2621440;                           // 2097152 f
    float* qstats = ws + 4718592;                         // 32 f
    unsigned short* valsT = (unsigned short*)(ws + 4718624);  // 32*64*1056 us
    unsigned short* E16 = (unsigned short*)(ws + 5799968);    // 16777216 us
    const bool useE16 = ws_size >= (size_t)14188576 * 4;

    hipMemsetAsync(qstats, 0, 32 * sizeof(float), stream);

    proj_kv_kernel<<<1024, 256, 0, stream>>>(c, Wk, Wv, sk, vals);
    softmax_m_kernel<<<B * K, 256, 0, stream>>>(sk);
    bn_values_kernel<<<M, 256, 0, stream>>>(vals, gv, bv);
    valsT_kernel<<<512, 256, 0, stream>>>(vals, valsT);
    content_lambda_kernel<<<B, 256, 0, stream>>>(sk, vals, valsT);
    proj_q_kernel<<<1024, 256, 0, stream>>>(x, Wq, qbuf, qstats);
    if (useE16) {
        e16_kernel<<<8192, 256, 0, stream>>>(E, E16);
        fused_mfma_kernel<true><<<1024, 256, 0, stream>>>(qbuf, E, E16, valsT,
                                                          qstats, gq, bq, out);
    } else {
        fused_mfma_kernel<false><<<1024, 256, 0, stream>>>(qbuf, E, E16, valsT,
                                                           qstats, gq, bq, out);
    }
}